// Round 5
// baseline (343.743 us; speedup 1.0000x reference)
//
#include <hip/hip_runtime.h>
#include <hip/hip_bf16.h>

#define NNODES 50000
#define NEDGES 600000
#define NGRAPHS 512
#define BN_EPS 1e-5f

typedef short bf16x8 __attribute__((ext_vector_type(8)));
typedef float f32x4 __attribute__((ext_vector_type(4)));

// split fp32 -> hi/lo bf16 (RNE); hi+lo carries ~16 mantissa bits (weights only)
__device__ __forceinline__ void bf_split(float x, ushort& h, ushort& l) {
    __hip_bfloat16 bh = __float2bfloat16(x);
    float r = x - __bfloat162float(bh);
    __hip_bfloat16 bl = __float2bfloat16(r);
    h = __builtin_bit_cast(ushort, bh);
    l = __builtin_bit_cast(ushort, bl);
}
__device__ __forceinline__ ushort f2b(float x) {
    return __builtin_bit_cast(ushort, __float2bfloat16(x));
}
__device__ __forceinline__ float b2f(ushort u) {
    union { uint i; float f; } c; c.i = ((uint)u) << 16; return c.f;
}
// bf16 pair unpack from a packed uint: lo = shift, hi = mask (1 VALU each)
__device__ __forceinline__ float blo(uint u) {
    union { uint i; float f; } c; c.i = u << 16; return c.f;
}
__device__ __forceinline__ float bhi(uint u) {
    union { uint i; float f; } c; c.i = u & 0xffff0000u; return c.f;
}

// ------------------------------------------------------------------- prep
// One dispatch: x->bf16 (blocks 0..3124), zero pooled (3125..3316), hist
// over edges (3317..5660; counts pre-zeroed via hipMemsetAsync), wsplit 6
// matrices in MFMA-FRAGMENT ORDER (5661..5756), row_ptr[N] init.
__global__ __launch_bounds__(256) void prep_kernel(
    const float* __restrict__ x, ushort* __restrict__ xh,
    float* __restrict__ pooled, const int* __restrict__ dst,
    int* __restrict__ counts, int* __restrict__ row_ptr,
    const float* W0, const float* W1, const float* W2, const float* W3,
    const float* W4, const float* W5, ushort* __restrict__ hi, ushort* __restrict__ lo) {
    int b = blockIdx.x, t = threadIdx.x;
    if (b < 3125) {                                 // x: 6.4M floats -> bf16
        int f4 = b * 512 + t * 2;
        float4 a0 = ((const float4*)x)[f4];
        float4 a1 = ((const float4*)x)[f4 + 1];
        ushort4 u0 = {f2b(a0.x), f2b(a0.y), f2b(a0.z), f2b(a0.w)};
        ushort4 u1 = {f2b(a1.x), f2b(a1.y), f2b(a1.z), f2b(a1.w)};
        int e0 = f4 * 4;
        *(ushort4*)(xh + e0) = u0;
        *(ushort4*)(xh + e0 + 4) = u1;
        if (b == 0 && t == 0) row_ptr[NNODES] = NEDGES;
    } else if (b < 3317) {                          // pooled: 512*384 floats
        ((float4*)pooled)[(b - 3125) * 256 + t] = make_float4(0.f, 0.f, 0.f, 0.f);
    } else if (b < 5661) {                          // hist: 600000 edges
        int i = (b - 3317) * 256 + t;
        if (i < NEDGES) atomicAdd(&counts[dst[i]], 1);
    } else {                                        // wsplit: 96 blocks
        int wb = b - 5661;
        const float* Ws[6] = {W0, W1, W2, W3, W4, W5};
        const float* W = Ws[wb >> 4];
        ushort* h = hi + (size_t)(wb >> 4) * 16384;
        ushort* l = lo + (size_t)(wb >> 4) * 16384;
        int chunk = wb & 15;
#pragma unroll
        for (int i = 0; i < 4; i++) {
            int idx = chunk * 1024 + i * 256 + t;   // 0..16383 frag-order slot
            int j    = idx & 7;
            int lane = (idx >> 3) & 63;
            int nt   = (idx >> 9) & 7;
            int kb   = (idx >> 12) & 3;
            int k = kb * 32 + ((lane >> 4) << 3) + j;
            int n = nt * 16 + (lane & 15);
            ushort hh, ll;
            bf_split(W[k * 128 + n], hh, ll);
            h[idx] = hh;
            l[idx] = ll;
        }
    }
}

// ---------------------------------------------------------------- CSR build
__global__ __launch_bounds__(256) void scan1_kernel(const int* __restrict__ counts,
                                                    int* __restrict__ partials, int n) {
    __shared__ int s[256];
    int i = blockIdx.x * 256 + threadIdx.x;
    int v = (i < n) ? counts[i] : 0;
    s[threadIdx.x] = v;
    __syncthreads();
    for (int off = 128; off > 0; off >>= 1) {
        if (threadIdx.x < off) s[threadIdx.x] += s[threadIdx.x + off];
        __syncthreads();
    }
    if (threadIdx.x == 0) partials[blockIdx.x] = s[0];
}

// scan3 with inline base reduction (no scan2 dispatch), nb<=256
__global__ __launch_bounds__(256) void scan3_kernel(const int* __restrict__ counts,
                                                    const int* __restrict__ partials,
                                                    int* __restrict__ row_ptr,
                                                    int* __restrict__ cursor, int n, int nb) {
    __shared__ int s[256];
    __shared__ int base_sh;
    int t = threadIdx.x;
    int pv = (t < (int)blockIdx.x && t < nb) ? partials[t] : 0;
    s[t] = pv;
    __syncthreads();
    for (int off = 128; off > 0; off >>= 1) {
        if (t < off) s[t] += s[t + off];
        __syncthreads();
    }
    if (t == 0) base_sh = s[0];
    __syncthreads();
    int base = base_sh;
    int i = blockIdx.x * 256 + t;
    int v = (i < n) ? counts[i] : 0;
    __syncthreads();
    s[t] = v;
    __syncthreads();
    for (int off = 1; off < 256; off <<= 1) {
        int nv = (t >= off) ? s[t - off] : 0;
        __syncthreads();
        s[t] += nv;
        __syncthreads();
    }
    if (i < n) {
        int ex = base + s[t] - v;   // exclusive
        row_ptr[i] = ex;
        cursor[i] = ex;
    }
}

__global__ __launch_bounds__(256) void scatter_kernel(const int* __restrict__ src,
                                                      const int* __restrict__ dst,
                                                      int* __restrict__ cursor,
                                                      int* __restrict__ esrc, int E) {
    int i = blockIdx.x * 256 + threadIdx.x;
    if (i < E) {
        int p = atomicAdd(&cursor[dst[i]], 1);
        esrc[p] = src[i];
    }
}

// ------------------------------------------------------------- aggregation
// R5: 4 nodes/wave, 16 lanes x 8 ch (uint4 = 16B/lane), DUAL 8-edge batch
// main loop: 16 outstanding row gathers per lane (256B in flight, 2x R4)
// to probe latency- vs fabric-bound. Accumulation = two sequential 8-edge
// pairwise trees in batch order -> bitwise-identical to R4/R2.
__global__ __launch_bounds__(256) void agg_kernel(
    const ushort* __restrict__ phi,
    const int* __restrict__ rp, const int* __restrict__ esrc,
    ushort* __restrict__ ohi, int n) {
    int wid  = (blockIdx.x * 256 + threadIdx.x) >> 6;
    int lane = threadIdx.x & 63;
    int node = wid * 4 + (lane >> 4);
    int q = lane & 15;                   // 16B granule: channels q*8..q*8+7
    if (node >= n) return;
    const uint4* xv = (const uint4*)phi; // row = 16 granules of 16B
    uint4 s0 = xv[(size_t)node * 16 + q];
    float acc[8];
    acc[0] = blo(s0.x); acc[1] = bhi(s0.x);
    acc[2] = blo(s0.y); acc[3] = bhi(s0.y);
    acc[4] = blo(s0.z); acc[5] = bhi(s0.z);
    acc[6] = blo(s0.w); acc[7] = bhi(s0.w);
    int e = rp[node], end = rp[node + 1];
    // dual-batch main: issue 16 gathers, then accumulate batch A, batch B
    for (; e + 16 <= end; e += 16) {
        int a0 = esrc[e],      a1 = esrc[e + 1],  a2 = esrc[e + 2],  a3 = esrc[e + 3];
        int a4 = esrc[e + 4],  a5 = esrc[e + 5],  a6 = esrc[e + 6],  a7 = esrc[e + 7];
        int b0 = esrc[e + 8],  b1 = esrc[e + 9],  b2 = esrc[e + 10], b3 = esrc[e + 11];
        int b4 = esrc[e + 12], b5 = esrc[e + 13], b6 = esrc[e + 14], b7 = esrc[e + 15];
        uint4 v0 = xv[(size_t)a0 * 16 + q];
        uint4 v1 = xv[(size_t)a1 * 16 + q];
        uint4 v2 = xv[(size_t)a2 * 16 + q];
        uint4 v3 = xv[(size_t)a3 * 16 + q];
        uint4 v4 = xv[(size_t)a4 * 16 + q];
        uint4 v5 = xv[(size_t)a5 * 16 + q];
        uint4 v6 = xv[(size_t)a6 * 16 + q];
        uint4 v7 = xv[(size_t)a7 * 16 + q];
        uint4 w0 = xv[(size_t)b0 * 16 + q];
        uint4 w1 = xv[(size_t)b1 * 16 + q];
        uint4 w2 = xv[(size_t)b2 * 16 + q];
        uint4 w3 = xv[(size_t)b3 * 16 + q];
        uint4 w4 = xv[(size_t)b4 * 16 + q];
        uint4 w5 = xv[(size_t)b5 * 16 + q];
        uint4 w6 = xv[(size_t)b6 * 16 + q];
        uint4 w7 = xv[(size_t)b7 * 16 + q];
        // batch A (exact R4 tree)
        acc[0] += ((blo(v0.x) + blo(v1.x)) + (blo(v2.x) + blo(v3.x))) +
                  ((blo(v4.x) + blo(v5.x)) + (blo(v6.x) + blo(v7.x)));
        acc[1] += ((bhi(v0.x) + bhi(v1.x)) + (bhi(v2.x) + bhi(v3.x))) +
                  ((bhi(v4.x) + bhi(v5.x)) + (bhi(v6.x) + bhi(v7.x)));
        acc[2] += ((blo(v0.y) + blo(v1.y)) + (blo(v2.y) + blo(v3.y))) +
                  ((blo(v4.y) + blo(v5.y)) + (blo(v6.y) + blo(v7.y)));
        acc[3] += ((bhi(v0.y) + bhi(v1.y)) + (bhi(v2.y) + bhi(v3.y))) +
                  ((bhi(v4.y) + bhi(v5.y)) + (bhi(v6.y) + bhi(v7.y)));
        acc[4] += ((blo(v0.z) + blo(v1.z)) + (blo(v2.z) + blo(v3.z))) +
                  ((blo(v4.z) + blo(v5.z)) + (blo(v6.z) + blo(v7.z)));
        acc[5] += ((bhi(v0.z) + bhi(v1.z)) + (bhi(v2.z) + bhi(v3.z))) +
                  ((bhi(v4.z) + bhi(v5.z)) + (bhi(v6.z) + bhi(v7.z)));
        acc[6] += ((blo(v0.w) + blo(v1.w)) + (blo(v2.w) + blo(v3.w))) +
                  ((blo(v4.w) + blo(v5.w)) + (blo(v6.w) + blo(v7.w)));
        acc[7] += ((bhi(v0.w) + bhi(v1.w)) + (bhi(v2.w) + bhi(v3.w))) +
                  ((bhi(v4.w) + bhi(v5.w)) + (bhi(v6.w) + bhi(v7.w)));
        // batch B (exact tree)
        acc[0] += ((blo(w0.x) + blo(w1.x)) + (blo(w2.x) + blo(w3.x))) +
                  ((blo(w4.x) + blo(w5.x)) + (blo(w6.x) + blo(w7.x)));
        acc[1] += ((bhi(w0.x) + bhi(w1.x)) + (bhi(w2.x) + bhi(w3.x))) +
                  ((bhi(w4.x) + bhi(w5.x)) + (bhi(w6.x) + bhi(w7.x)));
        acc[2] += ((blo(w0.y) + blo(w1.y)) + (blo(w2.y) + blo(w3.y))) +
                  ((blo(w4.y) + blo(w5.y)) + (blo(w6.y) + blo(w7.y)));
        acc[3] += ((bhi(w0.y) + bhi(w1.y)) + (bhi(w2.y) + bhi(w3.y))) +
                  ((bhi(w4.y) + bhi(w5.y)) + (bhi(w6.y) + bhi(w7.y)));
        acc[4] += ((blo(w0.z) + blo(w1.z)) + (blo(w2.z) + blo(w3.z))) +
                  ((blo(w4.z) + blo(w5.z)) + (blo(w6.z) + blo(w7.z)));
        acc[5] += ((bhi(w0.z) + bhi(w1.z)) + (bhi(w2.z) + bhi(w3.z))) +
                  ((bhi(w4.z) + bhi(w5.z)) + (bhi(w6.z) + bhi(w7.z)));
        acc[6] += ((blo(w0.w) + blo(w1.w)) + (blo(w2.w) + blo(w3.w))) +
                  ((blo(w4.w) + blo(w5.w)) + (blo(w6.w) + blo(w7.w)));
        acc[7] += ((bhi(w0.w) + bhi(w1.w)) + (bhi(w2.w) + bhi(w3.w))) +
                  ((bhi(w4.w) + bhi(w5.w)) + (bhi(w6.w) + bhi(w7.w)));
    }
    for (; e + 8 <= end; e += 8) {
        int i0 = esrc[e],     i1 = esrc[e + 1], i2 = esrc[e + 2], i3 = esrc[e + 3];
        int i4 = esrc[e + 4], i5 = esrc[e + 5], i6 = esrc[e + 6], i7 = esrc[e + 7];
        uint4 v0 = xv[(size_t)i0 * 16 + q];
        uint4 v1 = xv[(size_t)i1 * 16 + q];
        uint4 v2 = xv[(size_t)i2 * 16 + q];
        uint4 v3 = xv[(size_t)i3 * 16 + q];
        uint4 v4 = xv[(size_t)i4 * 16 + q];
        uint4 v5 = xv[(size_t)i5 * 16 + q];
        uint4 v6 = xv[(size_t)i6 * 16 + q];
        uint4 v7 = xv[(size_t)i7 * 16 + q];
        acc[0] += ((blo(v0.x) + blo(v1.x)) + (blo(v2.x) + blo(v3.x))) +
                  ((blo(v4.x) + blo(v5.x)) + (blo(v6.x) + blo(v7.x)));
        acc[1] += ((bhi(v0.x) + bhi(v1.x)) + (bhi(v2.x) + bhi(v3.x))) +
                  ((bhi(v4.x) + bhi(v5.x)) + (bhi(v6.x) + bhi(v7.x)));
        acc[2] += ((blo(v0.y) + blo(v1.y)) + (blo(v2.y) + blo(v3.y))) +
                  ((blo(v4.y) + blo(v5.y)) + (blo(v6.y) + blo(v7.y)));
        acc[3] += ((bhi(v0.y) + bhi(v1.y)) + (bhi(v2.y) + bhi(v3.y))) +
                  ((bhi(v4.y) + bhi(v5.y)) + (bhi(v6.y) + bhi(v7.y)));
        acc[4] += ((blo(v0.z) + blo(v1.z)) + (blo(v2.z) + blo(v3.z))) +
                  ((blo(v4.z) + blo(v5.z)) + (blo(v6.z) + blo(v7.z)));
        acc[5] += ((bhi(v0.z) + bhi(v1.z)) + (bhi(v2.z) + bhi(v3.z))) +
                  ((bhi(v4.z) + bhi(v5.z)) + (bhi(v6.z) + bhi(v7.z)));
        acc[6] += ((blo(v0.w) + blo(v1.w)) + (blo(v2.w) + blo(v3.w))) +
                  ((blo(v4.w) + blo(v5.w)) + (blo(v6.w) + blo(v7.w)));
        acc[7] += ((bhi(v0.w) + bhi(v1.w)) + (bhi(v2.w) + bhi(v3.w))) +
                  ((bhi(v4.w) + bhi(v5.w)) + (bhi(v6.w) + bhi(v7.w)));
    }
    for (; e + 2 <= end; e += 2) {
        int i0 = esrc[e], i1 = esrc[e + 1];
        uint4 v0 = xv[(size_t)i0 * 16 + q];
        uint4 v1 = xv[(size_t)i1 * 16 + q];
        acc[0] += blo(v0.x) + blo(v1.x); acc[1] += bhi(v0.x) + bhi(v1.x);
        acc[2] += blo(v0.y) + blo(v1.y); acc[3] += bhi(v0.y) + bhi(v1.y);
        acc[4] += blo(v0.z) + blo(v1.z); acc[5] += bhi(v0.z) + bhi(v1.z);
        acc[6] += blo(v0.w) + blo(v1.w); acc[7] += bhi(v0.w) + bhi(v1.w);
    }
    for (; e < end; e++) {
        uint4 v = xv[(size_t)esrc[e] * 16 + q];
        acc[0] += blo(v.x); acc[1] += bhi(v.x);
        acc[2] += blo(v.y); acc[3] += bhi(v.y);
        acc[4] += blo(v.z); acc[5] += bhi(v.z);
        acc[6] += blo(v.w); acc[7] += bhi(v.w);
    }
    uint4 o;
    o.x = (uint)f2b(acc[0]) | ((uint)f2b(acc[1]) << 16);
    o.y = (uint)f2b(acc[2]) | ((uint)f2b(acc[3]) << 16);
    o.z = (uint)f2b(acc[4]) | ((uint)f2b(acc[5]) << 16);
    o.w = (uint)f2b(acc[6]) | ((uint)f2b(acc[7]) << 16);
    *(uint4*)(ohi + (size_t)node * 128 + q * 8) = o;
}

// --------------------------------------------------------------- fused MLP
// C = act( BN_ReLU( A@W1 ) @ W2 ), 64-row tile x 128 threads (2 waves).
// PER-WAVE SHAPE UNCHANGED from proven R14: 64x64 wave tile, 4x4 frags,
// 32 MFMA/kb. W planes stored in MFMA-fragment order -> each bh/bl load is
// one coalesced contiguous 1KB wave transaction. Fused mean-pool epilogue.
template <bool RELU_OUT, bool WRITE_PLANES>
__global__ __launch_bounds__(128) void mlp_kernel(
    const ushort* __restrict__ Ah,
    const ushort* __restrict__ W1hi, const ushort* __restrict__ W1lo,
    const ushort* __restrict__ W2hi, const ushort* __restrict__ W2lo,
    const float* __restrict__ b1, const float* __restrict__ gm,
    const float* __restrict__ bt, const float* __restrict__ rm,
    const float* __restrict__ rv, const float* __restrict__ b2,
    ushort* __restrict__ Ch,
    const int* __restrict__ batch, float* __restrict__ pooled, int poff, int M) {
    __shared__ __align__(16) ushort smem[64 * 136];   // 17408 B
    __shared__ int bsm[64];
    // A dbuf: smem[buf*4096 + m*32 + k]  (8192 ushorts, fits in smem)
    // H / P:  smem[row*136 + col]
    const int t = threadIdx.x;            // 0..127
    const int lane = t & 63;
    const int wv = t >> 6;                // col half
    const int row0 = blockIdx.x * 64;
    const int g = lane >> 4, c = lane & 15;

    if (t < 64) bsm[t] = (row0 + t < M) ? batch[row0 + t] : -1;

    // staging: 256 16B-segs per kb; thread owns segs t and t+128
    const int m0 = t >> 2, k80 = (t & 3) * 8;
    const int m1 = m0 + 32;
    int r0 = row0 + m0; if (r0 >= M) r0 = M - 1;
    int r1 = row0 + m1; if (r1 >= M) r1 = M - 1;
    const size_t ga0 = (size_t)r0 * 128 + k80;
    const size_t ga1 = (size_t)r1 * 128 + k80;
    const int la0 = m0 * 32 + k80, la1 = m1 * 32 + k80;

    f32x4 acc[4][4];
#pragma unroll
    for (int i = 0; i < 4; i++)
#pragma unroll
        for (int j = 0; j < 4; j++) acc[i][j] = (f32x4){0.f, 0.f, 0.f, 0.f};

    uint4 ph0 = *(const uint4*)(Ah + ga0);
    uint4 ph1 = *(const uint4*)(Ah + ga1);
    *(uint4*)&smem[la0] = ph0;
    *(uint4*)&smem[la1] = ph1;
    __syncthreads();

    // ---------------- phase 1: A @ W1 (2 terms)
    int cur = 0;
    for (int kb = 0; kb < 4; kb++) {
        bf16x8 bh[4], bl[4];
#pragma unroll
        for (int ct = 0; ct < 4; ct++) {
            const size_t wo = (((size_t)kb * 8 + (wv * 4 + ct)) * 64 + lane) * 8;
            bh[ct] = *(const bf16x8*)(W1hi + wo);
            bl[ct] = *(const bf16x8*)(W1lo + wo);
        }
        if (kb < 3) {
            const size_t o = (size_t)(kb + 1) * 32;
            ph0 = *(const uint4*)(Ah + ga0 + o);
            ph1 = *(const uint4*)(Ah + ga1 + o);
        }
        bf16x8 ah[4];
#pragma unroll
        for (int rt = 0; rt < 4; rt++) {
            int off = cur * 4096 + (rt * 16 + c) * 32 + g * 8;
            ah[rt] = *(bf16x8*)&smem[off];
        }
#pragma unroll
        for (int rt = 0; rt < 4; rt++)
#pragma unroll
            for (int ct = 0; ct < 4; ct++) {
                acc[rt][ct] = __builtin_amdgcn_mfma_f32_16x16x32_bf16(ah[rt], bh[ct], acc[rt][ct], 0, 0, 0);
                acc[rt][ct] = __builtin_amdgcn_mfma_f32_16x16x32_bf16(ah[rt], bl[ct], acc[rt][ct], 0, 0, 0);
            }
        if (kb < 3) {
            *(uint4*)&smem[(cur ^ 1) * 4096 + la0] = ph0;
            *(uint4*)&smem[(cur ^ 1) * 4096 + la1] = ph1;
        }
        __syncthreads();   // final iter: all A reads done -> H may overwrite
        cur ^= 1;
    }

    // ---------------- BN + ReLU -> H (bf16)
    {
        float cs[4], ca[4];
#pragma unroll
        for (int ct = 0; ct < 4; ct++) {
            int n = wv * 64 + ct * 16 + c;
            float s = gm[n] * rsqrtf(rv[n] + BN_EPS);
            cs[ct] = s;
            ca[ct] = (b1[n] - rm[n]) * s + bt[n];
        }
#pragma unroll
        for (int rt = 0; rt < 4; rt++)
#pragma unroll
            for (int r = 0; r < 4; r++) {
                int row = rt * 16 + g * 4 + r;
#pragma unroll
                for (int ct = 0; ct < 4; ct++) {
                    int col = wv * 64 + ct * 16 + c;
                    float v = fmaxf(acc[rt][ct][r] * cs[ct] + ca[ct], 0.f);
                    smem[row * 136 + col] = f2b(v);
                }
            }
    }
    __syncthreads();

    // ---------------- phase 2: H @ W2 (2 terms)
#pragma unroll
    for (int i = 0; i < 4; i++)
#pragma unroll
        for (int j = 0; j < 4; j++) acc[i][j] = (f32x4){0.f, 0.f, 0.f, 0.f};

    for (int kb = 0; kb < 4; kb++) {
        bf16x8 bh[4], bl[4];
#pragma unroll
        for (int ct = 0; ct < 4; ct++) {
            const size_t wo = (((size_t)kb * 8 + (wv * 4 + ct)) * 64 + lane) * 8;
            bh[ct] = *(const bf16x8*)(W2hi + wo);
            bl[ct] = *(const bf16x8*)(W2lo + wo);
        }
        bf16x8 ah[4];
#pragma unroll
        for (int rt = 0; rt < 4; rt++) {
            int off = (rt * 16 + c) * 136 + kb * 32 + g * 8;
            ah[rt] = *(bf16x8*)&smem[off];
        }
#pragma unroll
        for (int rt = 0; rt < 4; rt++)
#pragma unroll
            for (int ct = 0; ct < 4; ct++) {
                acc[rt][ct] = __builtin_amdgcn_mfma_f32_16x16x32_bf16(ah[rt], bh[ct], acc[rt][ct], 0, 0, 0);
                acc[rt][ct] = __builtin_amdgcn_mfma_f32_16x16x32_bf16(ah[rt], bl[ct], acc[rt][ct], 0, 0, 0);
            }
    }
    __syncthreads();   // all H reads done -> P may overwrite smem

    // ---------------- epilogue: +b2 (,ReLU) -> bf16 plane + LDS P (bf16)
    {
        float ca2[4];
#pragma unroll
        for (int ct = 0; ct < 4; ct++) ca2[ct] = b2[wv * 64 + ct * 16 + c];
#pragma unroll
        for (int rt = 0; rt < 4; rt++)
#pragma unroll
            for (int r = 0; r < 4; r++) {
                int rl = rt * 16 + g * 4 + r;
                int row = row0 + rl;
                bool valid = row < M;
#pragma unroll
                for (int ct = 0; ct < 4; ct++) {
                    int col = wv * 64 + ct * 16 + c;
                    float v = acc[rt][ct][r] + ca2[ct];
                    if (RELU_OUT) v = fmaxf(v, 0.f);
                    ushort hh = f2b(valid ? v : 0.f);
                    smem[rl * 136 + col] = hh;
                    if (WRITE_PLANES && valid) Ch[(size_t)row * 128 + col] = hh;
                }
            }
    }
    __syncthreads();

    // ---------------- fused mean-pool contribution (batch is sorted)
    {
        int col = t;              // 0..127
        int gcur = bsm[0];
        float accp = 0.f;
#pragma unroll 8
        for (int r = 0; r < 64; r++) {
            int gg = bsm[r];
            if (gg != gcur) {     // block-uniform branch (sorted batch)
                if (gcur >= 0) atomicAdd(&pooled[gcur * 384 + poff + col], accp);
                accp = 0.f;
                gcur = gg;
            }
            accp += b2f(smem[r * 136 + col]);
        }
        if (gcur >= 0) atomicAdd(&pooled[gcur * 384 + poff + col], accp);
    }
}

// ------------------------------------------------------------------- final
__global__ __launch_bounds__(128) void final_kernel(const float* __restrict__ pooled,
                                                    const int* __restrict__ batch,
                                                    const float* __restrict__ W,
                                                    const float* __restrict__ b,
                                                    float* __restrict__ out, int n) {
    __shared__ float ps[384];
    int gph = blockIdx.x, t = threadIdx.x;
    int lo1 = 0, hi1 = n;
    while (lo1 < hi1) { int mid = (lo1 + hi1) >> 1; if (batch[mid] < gph) lo1 = mid + 1; else hi1 = mid; }
    int start = lo1;
    int lo2 = start, hi2 = n;
    while (lo2 < hi2) { int mid = (lo2 + hi2) >> 1; if (batch[mid] < gph + 1) lo2 = mid + 1; else hi2 = mid; }
    int cnt = lo2 - start;
    float inv = 1.f / (float)(cnt > 0 ? cnt : 1);
    for (int i = t; i < 384; i += 128) ps[i] = pooled[gph * 384 + i] * inv;
    __syncthreads();
    float acc = b[t];
#pragma unroll 8
    for (int k = 0; k < 384; k++) acc += ps[k] * W[k * 128 + t];
    out[gph * 128 + t] = acc;
}

// ------------------------------------------------------------------ launch
extern "C" void kernel_launch(void* const* d_in, const int* in_sizes, int n_in,
                              void* d_out, int out_size, void* d_ws, size_t ws_size,
                              hipStream_t stream) {
    const float* x     = (const float*)d_in[0];
    const int*   edge  = (const int*)d_in[1];
    const int*   batch = (const int*)d_in[2];
    const float* p[32];
    for (int i = 0; i < n_in && i < 32; i++) p[i] = (const float*)d_in[i];
    const float* lin_W = p[27];
    const float* lin_b = p[28];

    char* w = (char*)d_ws;
    auto alloc = [&](size_t bytes) { void* r = (void*)w; w += (bytes + 255) & ~(size_t)255; return r; };
    const size_t PL = (size_t)NNODES * 128;
    ushort* thi   = (ushort*)alloc(PL * 2);   // agg out plane
    ushort* xh0   = (ushort*)alloc(PL * 2);   // bf16(x); dead after agg L1
    ushort* p1h   = (ushort*)alloc(PL * 2);
    ushort* p2h   = xh0;                      // alias: xh0 dead before mlp L2 writes
    float* pooled = (float*)alloc((size_t)NGRAPHS * 384 * 4);
    int* counts   = (int*)alloc((size_t)NNODES * 4);
    int* cursor   = (int*)alloc((size_t)NNODES * 4);
    int* row_ptr  = (int*)alloc((size_t)(NNODES + 1) * 4);
    int* esrc     = (int*)alloc((size_t)NEDGES * 4);
    int* partials = (int*)alloc(256 * 4);
    ushort* wt_hi = (ushort*)alloc((size_t)6 * 16384 * 2);
    ushort* wt_lo = (ushort*)alloc((size_t)6 * 16384 * 2);

    const int* src = edge;
    const int* dst = edge + NEDGES;

    // --- zero counts (stream-ordered), then prep incl. hist + frag wsplit
    hipMemsetAsync(counts, 0, (size_t)NNODES * 4, stream);
    prep_kernel<<<5757, 256, 0, stream>>>(x, xh0, pooled, dst, counts, row_ptr,
                                          p[3], p[9], p[11], p[17], p[19], p[25],
                                          wt_hi, wt_lo);

    // --- CSR build: 3 dispatches (hist folded into prep)
    int nb = (NNODES + 255) / 256;  // 196
    scan1_kernel<<<nb, 256, 0, stream>>>(counts, partials, NNODES);
    scan3_kernel<<<nb, 256, 0, stream>>>(counts, partials, row_ptr, cursor, NNODES, nb);
    scatter_kernel<<<(NEDGES + 255) / 256, 256, 0, stream>>>(src, dst, cursor, esrc, NEDGES);

    // --- 3 GIN layers (mlp fuses the mean-pool contribution)
    int mlp_grid = (NNODES + 63) / 64;              // 782
    int agg_grid = (NNODES / 4 * 64 + 255) / 256;   // 3125

    // layer 1 (self from bf16 plane — same rounding class as neighbors)
    agg_kernel<<<agg_grid, 256, 0, stream>>>(xh0, row_ptr, esrc, thi, NNODES);
    mlp_kernel<true, true><<<mlp_grid, 128, 0, stream>>>(thi,
        wt_hi + 0 * 16384, wt_lo + 0 * 16384, wt_hi + 1 * 16384, wt_lo + 1 * 16384,
        p[4], p[5], p[6], p[7], p[8], p[10], p1h, batch, pooled, 0, NNODES);
    // layer 2
    agg_kernel<<<agg_grid, 256, 0, stream>>>(p1h, row_ptr, esrc, thi, NNODES);
    mlp_kernel<true, true><<<mlp_grid, 128, 0, stream>>>(thi,
        wt_hi + 2 * 16384, wt_lo + 2 * 16384, wt_hi + 3 * 16384, wt_lo + 3 * 16384,
        p[12], p[13], p[14], p[15], p[16], p[18], p2h, batch, pooled, 128, NNODES);
    // layer 3 (no relu, no plane writes — pool-only output)
    agg_kernel<<<agg_grid, 256, 0, stream>>>(p2h, row_ptr, esrc, thi, NNODES);
    mlp_kernel<false, false><<<mlp_grid, 128, 0, stream>>>(thi,
        wt_hi + 4 * 16384, wt_lo + 4 * 16384, wt_hi + 5 * 16384, wt_lo + 5 * 16384,
        p[20], p[21], p[22], p[23], p[24], p[26], nullptr, batch, pooled, 256, NNODES);

    // --- final linear on mean-pooled JK-concat
    final_kernel<<<NGRAPHS, 128, 0, stream>>>(pooled, batch, lin_W, lin_b,
                                              (float*)d_out, NNODES);
}